// Round 1
// baseline (553.765 us; speedup 1.0000x reference)
//
#include <hip/hip_runtime.h>

// GRU decoder: B=32768 batch, T=48 steps, F=16 features, H=32 hidden.
// Layout: 32 lanes per batch element; lane j owns hidden unit j.
// Weights (columns j, 32+j, 64+j of kernel/recurrent_kernel) live in VGPRs.
// Cross-lane: ds_swizzle broadcast of h[k] (imm offset, no addr setup),
// butterfly reduction for the Dense(32->1) output.

constexpr int T_STEPS = 48;
constexpr int F_DIM   = 16;
constexpr int H_DIM   = 32;

__global__ __launch_bounds__(256, 2)
void gru_decoder_kernel(const float* __restrict__ feat,      // [B,T,F]
                        const float* __restrict__ init_in,   // [B,1]
                        const float* __restrict__ init_h,    // [B,H]
                        const float* __restrict__ Wk,        // [17,96]
                        const float* __restrict__ Rk,        // [32,96]
                        const float* __restrict__ bx,        // [96]
                        const float* __restrict__ bh,        // [96]
                        const float* __restrict__ dw,        // [32]
                        const float* __restrict__ db,        // [1]
                        float* __restrict__ out)             // [B,T]
{
    const int tid = blockIdx.x * 256 + threadIdx.x;
    const int b = tid >> 5;   // batch element (group of 32 lanes)
    const int j = tid & 31;   // hidden unit owned by this lane

    // ---- load weight columns into registers (one-time, coalesced) ----
    float Wz[17], Wr[17], Wh[17];
#pragma unroll
    for (int k = 0; k < 17; ++k) {
        Wz[k] = Wk[k * 96 + j];
        Wr[k] = Wk[k * 96 + 32 + j];
        Wh[k] = Wk[k * 96 + 64 + j];
    }
    float Rz[32], Rr[32], Rh[32];
#pragma unroll
    for (int k = 0; k < 32; ++k) {
        Rz[k] = Rk[k * 96 + j];
        Rr[k] = Rk[k * 96 + 32 + j];
        Rh[k] = Rk[k * 96 + 64 + j];
    }
    const float bz  = bx[j]      + bh[j];        // z-gate bias (combined)
    const float br  = bx[32 + j] + bh[32 + j];   // r-gate bias (combined)
    const float bxh = bx[64 + j];                // candidate: x-side bias
    const float bhh = bh[64 + j];                // candidate: h-side bias (inside r*)
    const float dwj = dw[j];
    const float dbs = db[0];

    float h  = init_h[(size_t)b * H_DIM + j];
    float po = init_in[b];                       // prev output (wave-group uniform)

    const float* fb = feat + (size_t)b * (T_STEPS * F_DIM);
    float*       ob = out  + (size_t)b * T_STEPS;

    for (int t = 0; t < T_STEPS; ++t) {
        // all 32 lanes of the group load the same 64B -> single L1 transaction
        const float4 f0 = *(const float4*)(fb + t * F_DIM + 0);
        const float4 f1 = *(const float4*)(fb + t * F_DIM + 4);
        const float4 f2 = *(const float4*)(fb + t * F_DIM + 8);
        const float4 f3 = *(const float4*)(fb + t * F_DIM + 12);
        float x[17] = { po, f0.x, f0.y, f0.z, f0.w, f1.x, f1.y, f1.z, f1.w,
                        f2.x, f2.y, f2.z, f2.w, f3.x, f3.y, f3.z, f3.w };

        float mz = bz, mr = br, mxh = bxh, mhh = bhh;
#pragma unroll
        for (int k = 0; k < 17; ++k) {
            mz  = fmaf(x[k], Wz[k], mz);
            mr  = fmaf(x[k], Wr[k], mr);
            mxh = fmaf(x[k], Wh[k], mxh);
        }

        // broadcast h[k] to all lanes of the 32-lane group via ds_swizzle
        // bit-mode: and=0, or=K, xor=0 -> offset = K<<5 (operates per 32-half)
#define STEPK(K) { float hk = __int_as_float(                                  \
                     __builtin_amdgcn_ds_swizzle(__float_as_int(h), ((K) << 5))); \
                   mz  = fmaf(hk, Rz[K], mz);                                  \
                   mr  = fmaf(hk, Rr[K], mr);                                  \
                   mhh = fmaf(hk, Rh[K], mhh); }
        STEPK(0)  STEPK(1)  STEPK(2)  STEPK(3)  STEPK(4)  STEPK(5)  STEPK(6)  STEPK(7)
        STEPK(8)  STEPK(9)  STEPK(10) STEPK(11) STEPK(12) STEPK(13) STEPK(14) STEPK(15)
        STEPK(16) STEPK(17) STEPK(18) STEPK(19) STEPK(20) STEPK(21) STEPK(22) STEPK(23)
        STEPK(24) STEPK(25) STEPK(26) STEPK(27) STEPK(28) STEPK(29) STEPK(30) STEPK(31)
#undef STEPK

        const float ez = __expf(-mz);
        const float z  = __builtin_amdgcn_rcpf(1.0f + ez);
        const float er = __expf(-mr);
        const float r  = __builtin_amdgcn_rcpf(1.0f + er);
        const float ta = mxh + r * mhh;
        const float e2 = __expf(2.0f * ta);
        const float hh = 1.0f - 2.0f * __builtin_amdgcn_rcpf(e2 + 1.0f); // tanh
        h = fmaf(z, h - hh, hh);   // z*h + (1-z)*hh

        // Dense(32 -> 1): butterfly sum within the 32-lane group
        float v = h * dwj;
        // bit-mode xor: and=0x1f, or=0, xor=S -> offset = (S<<10)|0x1f
#define RED(S) v += __int_as_float(                                            \
                 __builtin_amdgcn_ds_swizzle(__float_as_int(v), (((S) << 10) | 0x1f)));
        RED(1) RED(2) RED(4) RED(8) RED(16)
#undef RED
        const float o = v + dbs;
        if (j == 0) ob[t] = o;
        po = o;   // all lanes hold the group sum after the butterfly
    }
}

extern "C" void kernel_launch(void* const* d_in, const int* in_sizes, int n_in,
                              void* d_out, int out_size, void* d_ws, size_t ws_size,
                              hipStream_t stream) {
    const float* feat    = (const float*)d_in[0];
    const float* init_in = (const float*)d_in[1];
    const float* init_h  = (const float*)d_in[2];
    const float* Wk      = (const float*)d_in[3];
    const float* Rk      = (const float*)d_in[4];
    const float* bx      = (const float*)d_in[5];
    const float* bh      = (const float*)d_in[6];
    const float* dw      = (const float*)d_in[7];
    const float* db      = (const float*)d_in[8];
    float* out           = (float*)d_out;

    const int B = in_sizes[2] / H_DIM;          // 32768
    dim3 grid((unsigned)((B * 32) / 256));      // 32 lanes per batch element
    dim3 block(256);
    hipLaunchKernelGGL(gru_decoder_kernel, grid, block, 0, stream,
                       feat, init_in, init_h, Wk, Rk, bx, bh, dw, db, out);
}

// Round 2
// 217.801 us; speedup vs baseline: 2.5425x; 2.5425x over previous
//
#include <hip/hip_runtime.h>

// GRU decoder via MFMA: B=32768, T=48, F=16, H=32 (3H=96 gate outputs).
// Each wave owns 16 batch rows for all 48 steps.
//   A-operand  = [16 batch rows x K=32] (x-input padded, h exact)
//   B-operand  = weight tiles [K=32 x 16 cols], 6 N-tiles cover 3H=96
//   C/D layout = col=lane&15, row=(lane>>4)*4+reg   (verified m89/m91)
//   A   layout = A[m=lane&15][k=(lane>>4)*8+j]      (verified m120)
//   B   layout = B[k=(lane>>4)*8+j][n=lane&15]
// h lives in C-layout registers; C->A transform via wave-private LDS
// (no __syncthreads needed: single-wave producer/consumer, in-order DS pipe).
// x K-slots: k=0..15 = feat[0..15] (aligned 32B loads), k=17 = prev_out,
// rest zero; kernel rows reordered to match when staging B-frags.

typedef __attribute__((ext_vector_type(8))) short short8;
typedef __attribute__((ext_vector_type(4))) float f32x4;

constexpr int T_STEPS = 48;
constexpr int F_DIM   = 16;
constexpr int H_DIM   = 32;
constexpr int ROW_B   = 144;                 // LDS h-row stride (16B aligned, conflict-spreading)
constexpr int WAVE_LDS = 16 * ROW_B + 64;    // h tile + o_buf(16 floats)

__device__ __forceinline__ short bf16r(float x) {   // RNE float->bf16
    union { float f; unsigned u; } v; v.f = x;
    unsigned r = v.u + 0x7FFF + ((v.u >> 16) & 1);
    return (short)(r >> 16);
}
__device__ __forceinline__ float fsig(float x) {
    return __builtin_amdgcn_rcpf(1.0f + __expf(-x));
}
__device__ __forceinline__ float ftanh(float x) {
    return 1.0f - 2.0f * __builtin_amdgcn_rcpf(__expf(2.0f * x) + 1.0f);
}
#define MFMA(a, b, c) __builtin_amdgcn_mfma_f32_16x16x32_bf16(a, b, c, 0, 0, 0)
#define SWZ(v, m) __int_as_float(__builtin_amdgcn_ds_swizzle(__float_as_int(v), (((m) << 10) | 0x1f)))

__global__ __launch_bounds__(256, 2)
void gru_mfma(const float* __restrict__ feat,     // [B,T,F]
              const float* __restrict__ init_in,  // [B,1]
              const float* __restrict__ init_h,   // [B,H]
              const float* __restrict__ Wk,       // [17,96]
              const float* __restrict__ Rk,       // [32,96]
              const float* __restrict__ bx,       // [96]
              const float* __restrict__ bh,       // [96]
              const float* __restrict__ dw,       // [32]
              const float* __restrict__ db,       // [1]
              float* __restrict__ out)            // [B,T]
{
    __shared__ char lds[4 * WAVE_LDS];
    const int lane = threadIdx.x & 63;
    const int wave = threadIdx.x >> 6;
    const int ln   = lane & 15;
    const int quad = lane >> 4;
    const int b0   = (blockIdx.x * 4 + wave) * 16;

    char*  hb   = lds + wave * WAVE_LDS;
    float* obuf = (float*)(hb + 16 * ROW_B);

    // ---- stage weights as B-fragments (resident: 12 x 4 VGPRs) ----
    short8 Wf[6], Rf[6];
#pragma unroll
    for (int tn = 0; tn < 6; ++tn) {
        short8 w, r;
#pragma unroll
        for (int j = 0; j < 8; ++j) {
            const int k = quad * 8 + j;
            const int n = tn * 16 + ln;
            // x K-slot k: 0..15 -> kernel row k+1 (features), 17 -> kernel row 0 (prev_out)
            float wv = (k < 16) ? Wk[(k + 1) * 96 + n] : ((k == 17) ? Wk[n] : 0.0f);
            w[j] = bf16r(wv);
            r[j] = bf16r(Rk[k * 96 + n]);    // k = 0..31 exactly covers H
        }
        Wf[tn] = w; Rf[tn] = r;
    }

    float bz[2], brr[2], bxh[2], bhh[2], dwv[2];
#pragma unroll
    for (int tn = 0; tn < 2; ++tn) {
        const int n = tn * 16 + ln;
        bz[tn]  = bx[n] + bh[n];
        brr[tn] = bx[32 + n] + bh[32 + n];
        bxh[tn] = bx[64 + n];                // x-side candidate bias
        bhh[tn] = bh[64 + n];                // h-side candidate bias (inside r*)
        dwv[tn] = dw[n];
    }
    const float dbs = db[0];

    // ---- initial state: h in C-layout regs + A-frag, prev_out ----
    f32x4 hc[2];
#pragma unroll
    for (int tn = 0; tn < 2; ++tn)
#pragma unroll
        for (int i = 0; i < 4; ++i)
            hc[tn][i] = init_h[(size_t)(b0 + quad * 4 + i) * H_DIM + tn * 16 + ln];
    short8 hA;
#pragma unroll
    for (int j = 0; j < 8; ++j)
        hA[j] = bf16r(init_h[(size_t)(b0 + ln) * H_DIM + quad * 8 + j]);
    float po = init_in[b0 + ln];

    const float* fp = feat + (size_t)(b0 + ln) * T_STEPS * F_DIM;

    for (int t = 0; t < T_STEPS; ++t) {
        // ---- x A-fragment ----
        short8 xA;
        if (quad < 2) {   // k = quad*8 .. quad*8+7 -> feat[k], two aligned 16B loads
            f32x4 a = *(const f32x4*)(fp + t * F_DIM + quad * 8);
            f32x4 b = *(const f32x4*)(fp + t * F_DIM + quad * 8 + 4);
#pragma unroll
            for (int j = 0; j < 4; ++j) { xA[j] = bf16r(a[j]); xA[4 + j] = bf16r(b[j]); }
        } else {
            xA = (short8)(short)0;
            if (quad == 2) xA[1] = bf16r(po);   // k = 17
        }

        // ---- 12 MFMAs: z,r combined x+h; candidate split x / h ----
        f32x4 aZ[2], aR[2], aXH[2], aHH[2];
#pragma unroll
        for (int tn = 0; tn < 2; ++tn) {
            aZ[tn]  = (f32x4){bz[tn],  bz[tn],  bz[tn],  bz[tn]};
            aR[tn]  = (f32x4){brr[tn], brr[tn], brr[tn], brr[tn]};
            aXH[tn] = (f32x4){bxh[tn], bxh[tn], bxh[tn], bxh[tn]};
            aHH[tn] = (f32x4){bhh[tn], bhh[tn], bhh[tn], bhh[tn]};
            aZ[tn]  = MFMA(xA, Wf[tn],     aZ[tn]);
            aZ[tn]  = MFMA(hA, Rf[tn],     aZ[tn]);
            aR[tn]  = MFMA(xA, Wf[2 + tn], aR[tn]);
            aR[tn]  = MFMA(hA, Rf[2 + tn], aR[tn]);
            aXH[tn] = MFMA(xA, Wf[4 + tn], aXH[tn]);
            aHH[tn] = MFMA(hA, Rf[4 + tn], aHH[tn]);
        }

        // ---- gates (pure in-register: all C-tiles share lane mapping) ----
        float p[4] = {0.f, 0.f, 0.f, 0.f};
#pragma unroll
        for (int tn = 0; tn < 2; ++tn) {
#pragma unroll
            for (int i = 0; i < 4; ++i) {
                const float zz = fsig(aZ[tn][i]);
                const float rr = fsig(aR[tn][i]);
                const float cc = ftanh(aXH[tn][i] + rr * aHH[tn][i]);
                const float hn = cc + zz * (hc[tn][i] - cc);
                hc[tn][i] = hn;
                p[i] += hn * dwv[tn];
            }
        }

        // ---- Dense(32->1): butterfly over lane bits 0..3 (within quad) ----
#pragma unroll
        for (int i = 0; i < 4; ++i) {
            p[i] += SWZ(p[i], 1);
            p[i] += SWZ(p[i], 2);
            p[i] += SWZ(p[i], 4);
            p[i] += SWZ(p[i], 8);
        }

        if (ln == 0) {
#pragma unroll
            for (int i = 0; i < 4; ++i) {
                const float o = p[i] + dbs;
                out[(size_t)(b0 + quad * 4 + i) * T_STEPS + t] = o;
                obuf[quad * 4 + i] = o;
            }
        }

        // ---- h_new: C-layout -> LDS (bf16) -> A-frag for next step ----
#pragma unroll
        for (int tn = 0; tn < 2; ++tn)
#pragma unroll
            for (int i = 0; i < 4; ++i)
                *(short*)(hb + (quad * 4 + i) * ROW_B + (tn * 16 + ln) * 2) = bf16r(hc[tn][i]);

        hA = *(const short8*)(hb + ln * ROW_B + quad * 16);
        po = obuf[ln];
    }
}

extern "C" void kernel_launch(void* const* d_in, const int* in_sizes, int n_in,
                              void* d_out, int out_size, void* d_ws, size_t ws_size,
                              hipStream_t stream) {
    const float* feat    = (const float*)d_in[0];
    const float* init_in = (const float*)d_in[1];
    const float* init_h  = (const float*)d_in[2];
    const float* Wk      = (const float*)d_in[3];
    const float* Rk      = (const float*)d_in[4];
    const float* bx      = (const float*)d_in[5];
    const float* bh      = (const float*)d_in[6];
    const float* dw      = (const float*)d_in[7];
    const float* db      = (const float*)d_in[8];
    float* out           = (float*)d_out;

    const int B = in_sizes[2] / H_DIM;        // 32768
    dim3 grid((unsigned)(B / 64));            // 16 rows/wave * 4 waves/block
    dim3 block(256);
    hipLaunchKernelGGL(gru_mfma, grid, block, 0, stream,
                       feat, init_in, init_h, Wk, Rk, bx, bh, dw, db, out);
}

// Round 3
// 216.376 us; speedup vs baseline: 2.5593x; 1.0066x over previous
//
#include <hip/hip_runtime.h>

// GRU decoder via MFMA, round 3: B=32768, T=48, F=16, H=32.
// Wave owns 16 batch rows for all 48 steps (2048 waves = 2/SIMD).
// Changes vs round 2:
//  - feat software-pipelined (prefetch t+1 during step t) -> HBM latency off chain
//  - Dense(32->1) via extra MFMA with dw replicated in all 16 B-cols:
//      oD[m][n] = sum_k h[m][k] dw[k] + db  (same value in every col)
//    -> every lane holds out for its 4 batch rows; butterfly + obuf GONE.
//    prev_out enters mx as a rank-1 VALU update (po[i]*W_row0[n]) on C-init,
//    so the x A-frag is features-only (k=0..15, upper K half zero).
//  - bf16 staging packed via u32+0x8000 then v_perm_b32 (3 ops / 2 values).
// Layouts (verified m89/m91/m120):
//   C/D: col=lane&15, row=(lane>>4)*4+reg ; A: A[m=lane&15][k=(lane>>4)*8+j]
//   B:   B[k=(lane>>4)*8+j][n=lane&15]
// h C->A transform via wave-private LDS (8x ds_write_b16 + 1x ds_read_b128).

typedef __attribute__((ext_vector_type(8))) short short8;
typedef __attribute__((ext_vector_type(4))) float f32x4;

constexpr int T_STEPS = 48;
constexpr int F_DIM   = 16;
constexpr int H_DIM   = 32;
constexpr int ROW_SH  = 40;              // shorts per LDS h-row (32 + 8 pad; 80 B, 16B-aligned)
constexpr int WAVE_SH = 16 * ROW_SH;     // 1280 B per wave

union S8 { short8 s; unsigned u[4]; };

__device__ __forceinline__ unsigned pk_bf16(float hi, float lo) {
    // (bf16(hi)<<16)|bf16(lo), round-half-up: +0x8000 then take high halves
    return __builtin_amdgcn_perm(__float_as_uint(hi) + 0x8000u,
                                 __float_as_uint(lo) + 0x8000u, 0x07060302u);
}
__device__ __forceinline__ short bf16s(float x) {
    return (short)((__float_as_uint(x) + 0x8000u) >> 16);
}
__device__ __forceinline__ float fsig(float x) {
    return __builtin_amdgcn_rcpf(1.0f + __expf(-x));
}
__device__ __forceinline__ float ftanh(float x) {
    return 1.0f - 2.0f * __builtin_amdgcn_rcpf(__expf(2.0f * x) + 1.0f);
}
#define MFMA(a, b, c) __builtin_amdgcn_mfma_f32_16x16x32_bf16(a, b, c, 0, 0, 0)

__global__ __launch_bounds__(256, 2)
void gru_mfma3(const float* __restrict__ feat,     // [B,T,F]
               const float* __restrict__ init_in,  // [B,1]
               const float* __restrict__ init_h,   // [B,H]
               const float* __restrict__ Wk,       // [17,96]
               const float* __restrict__ Rk,       // [32,96]
               const float* __restrict__ bx,       // [96]
               const float* __restrict__ bh,       // [96]
               const float* __restrict__ dw,       // [32]
               const float* __restrict__ db,       // [1]
               float* __restrict__ out)            // [B,T]
{
    __shared__ __align__(16) short hsh[4 * WAVE_SH];
    const int lane = threadIdx.x & 63;
    const int wave = threadIdx.x >> 6;
    const int ln   = lane & 15;
    const int quad = lane >> 4;
    const int b0   = (blockIdx.x * 4 + wave) * 16;
    short* hbW = hsh + wave * WAVE_SH;
    short* hwr = hbW + quad * 4 * ROW_SH + ln;        // write base (row quad*4, col ln)
    const short8* hrd = (const short8*)(hbW + ln * ROW_SH + quad * 8);

    // ---- weight B-fragments (resident: 13 x 4 VGPRs) ----
    S8 Wf[6], Rf[6], Dwf;
#pragma unroll
    for (int tn = 0; tn < 6; ++tn) {
#pragma unroll
        for (int j = 0; j < 8; ++j) {
            const int k = quad * 8 + j;
            const int n = tn * 16 + ln;
            const float wv = (k < 16) ? Wk[(size_t)(k + 1) * 96 + n] : 0.0f;  // rows 1..16 = features
            Wf[tn].s[j] = bf16s(wv);
            Rf[tn].s[j] = bf16s(Rk[(size_t)k * 96 + n]);
        }
    }
#pragma unroll
    for (int j = 0; j < 8; ++j) Dwf.s[j] = bf16s(dw[quad * 8 + j]);  // replicated over n

    float bzv[2], brv[2], bxhv[2], bhhv[2], wpz[2], wpr[2], wph[2];
#pragma unroll
    for (int tn = 0; tn < 2; ++tn) {
        const int n = tn * 16 + ln;
        bzv[tn]  = bx[n] + bh[n];
        brv[tn]  = bx[32 + n] + bh[32 + n];
        bxhv[tn] = bx[64 + n];           // candidate x-side bias
        bhhv[tn] = bh[64 + n];           // candidate h-side bias (inside r*)
        wpz[tn]  = Wk[n];                // kernel row 0 = prev_out weights
        wpr[tn]  = Wk[32 + n];
        wph[tn]  = Wk[64 + n];
    }
    const float dbs = db[0];
    const f32x4 dbc = {dbs, dbs, dbs, dbs};

    // ---- initial state ----
    f32x4 hc[2];
#pragma unroll
    for (int tn = 0; tn < 2; ++tn)
#pragma unroll
        for (int i = 0; i < 4; ++i)
            hc[tn][i] = init_h[(size_t)(b0 + quad * 4 + i) * H_DIM + tn * 16 + ln];
    S8 ha;
    {
        const float* hp = init_h + (size_t)(b0 + ln) * H_DIM + quad * 8;
        const f32x4 a = *(const f32x4*)hp;
        const f32x4 b = *(const f32x4*)(hp + 4);
        ha.u[0] = pk_bf16(a[1], a[0]); ha.u[1] = pk_bf16(a[3], a[2]);
        ha.u[2] = pk_bf16(b[1], b[0]); ha.u[3] = pk_bf16(b[3], b[2]);
    }
    f32x4 po;
#pragma unroll
    for (int i = 0; i < 4; ++i) po[i] = init_in[b0 + quad * 4 + i];

    float* outB = out + (size_t)(b0 + quad * 4) * T_STEPS;

    // ---- feat prefetch for t=0 (quads 0/2 load first half, 1/3 second) ----
    const float* fqb = feat + (size_t)(b0 + ln) * (T_STEPS * F_DIM) + (quad & 1) * 8;
    f32x4 pa = *(const f32x4*)(fqb);
    f32x4 pb = *(const f32x4*)(fqb + 4);

    f32x4 oD = MFMA(ha.s, Dwf.s, dbc);   // junk at t=0 (out(-1)), never stored

    for (int t = 0; t < T_STEPS; ++t) {
        if (t > 0) {                      // oD = out(t-1), replicated across ln
            if (ln == 0) {
#pragma unroll
                for (int i = 0; i < 4; ++i) outB[i * T_STEPS + (t - 1)] = oD[i];
            }
            po = oD;
        }

        // x A-frag from prefetched regs; zero quads 2,3 (K upper half)
        S8 xa;
        xa.u[0] = pk_bf16(pa[1], pa[0]); xa.u[1] = pk_bf16(pa[3], pa[2]);
        xa.u[2] = pk_bf16(pb[1], pb[0]); xa.u[3] = pk_bf16(pb[3], pb[2]);
        const unsigned zm = (quad < 2) ? 0xFFFFFFFFu : 0u;
        xa.u[0] &= zm; xa.u[1] &= zm; xa.u[2] &= zm; xa.u[3] &= zm;

        // prefetch feat(t+1)
        const int t1 = (t < T_STEPS - 1) ? t + 1 : T_STEPS - 1;
        pa = *(const f32x4*)(fqb + t1 * F_DIM);
        pb = *(const f32x4*)(fqb + t1 * F_DIM + 4);

        // C-inits: bias + prev_out rank-1 term
        f32x4 aZ[2], aR[2], aXH[2], aHH[2];
#pragma unroll
        for (int tn = 0; tn < 2; ++tn)
#pragma unroll
            for (int i = 0; i < 4; ++i) {
                aZ[tn][i]  = fmaf(po[i], wpz[tn], bzv[tn]);
                aR[tn][i]  = fmaf(po[i], wpr[tn], brv[tn]);
                aXH[tn][i] = fmaf(po[i], wph[tn], bxhv[tn]);
                aHH[tn][i] = bhhv[tn];
            }
#pragma unroll
        for (int tn = 0; tn < 2; ++tn) {
            aZ[tn]  = MFMA(xa.s, Wf[tn].s,     aZ[tn]);
            aZ[tn]  = MFMA(ha.s, Rf[tn].s,     aZ[tn]);
            aR[tn]  = MFMA(xa.s, Wf[2 + tn].s, aR[tn]);
            aR[tn]  = MFMA(ha.s, Rf[2 + tn].s, aR[tn]);
            aXH[tn] = MFMA(xa.s, Wf[4 + tn].s, aXH[tn]);
            aHH[tn] = MFMA(ha.s, Rf[4 + tn].s, aHH[tn]);
        }

        // gates + h_new; write bf16 h to LDS as computed
#pragma unroll
        for (int tn = 0; tn < 2; ++tn)
#pragma unroll
            for (int i = 0; i < 4; ++i) {
                const float zz = fsig(aZ[tn][i]);
                const float rr = fsig(aR[tn][i]);
                const float cc = ftanh(aXH[tn][i] + rr * aHH[tn][i]);
                const float hn = cc + zz * (hc[tn][i] - cc);
                hc[tn][i] = hn;
                hwr[i * ROW_SH + tn * 16] = bf16s(hn);
            }

        // h C-layout -> A-frag for next step (wave-private, in-order DS)
        ha.s = *hrd;
        oD = MFMA(ha.s, Dwf.s, dbc);      // out(t)
    }

    if (ln == 0) {
#pragma unroll
        for (int i = 0; i < 4; ++i) outB[i * T_STEPS + (T_STEPS - 1)] = oD[i];
    }
}

extern "C" void kernel_launch(void* const* d_in, const int* in_sizes, int n_in,
                              void* d_out, int out_size, void* d_ws, size_t ws_size,
                              hipStream_t stream) {
    const float* feat    = (const float*)d_in[0];
    const float* init_in = (const float*)d_in[1];
    const float* init_h  = (const float*)d_in[2];
    const float* Wk      = (const float*)d_in[3];
    const float* Rk      = (const float*)d_in[4];
    const float* bx      = (const float*)d_in[5];
    const float* bh      = (const float*)d_in[6];
    const float* dw      = (const float*)d_in[7];
    const float* db      = (const float*)d_in[8];
    float* out           = (float*)d_out;

    const int B = in_sizes[2] / H_DIM;      // 32768
    dim3 grid((unsigned)(B / 64));          // 16 rows/wave * 4 waves/block
    dim3 block(256);
    hipLaunchKernelGGL(gru_mfma3, grid, block, 0, stream,
                       feat, init_in, init_h, Wk, Rk, bx, bh, dw, db, out);
}

// Round 4
// 198.577 us; speedup vs baseline: 2.7887x; 1.0896x over previous
//
#include <hip/hip_runtime.h>

// GRU decoder via MFMA, round 4: B=32768, T=48, F=16, H=32.
// Wave owns 16 batch rows for all 48 steps (2048 waves = 2/SIMD).
// Changes vs round 3 (which was chain-bound on in-loop global stores):
//  - TRANSPOSED formulation: D = MFMA(A=weights, B=data) so
//      D[m=gatecol][n=batch];  C-layout col(lane&15)=batch, row(quad*4+reg)=gate col.
//    Fragment register CONTENTS identical to round 3 (A/B layouts are
//    transposes with the same lane mapping) -- only operand order swaps.
//  - Dense(32->1): per-lane partial + xor16 ds_swizzle + xor32 ds_bpermute
//    (po replicated across quads, exactly where the rank-1 C-init needs it).
//    No MFMA on the po path.
//  - NO global stores in the loop: outputs go to a wave-private LDS buffer,
//    flushed once at the end with coalesced dwordx4 stores. Loop has no
//    vmcnt(0) store-drain -> feat prefetch finally lives.
//  - h C->B transform: 4x ds_write_b32 (bf16-packed pairs) + 1x ds_read_b128.
// Layouts (verified m89/m91/m120):
//   C/D: col=lane&15, row=(lane>>4)*4+reg ; A[m=lane&15][k=(lane>>4)*8+j]
//   B[k=(lane>>4)*8+j][n=lane&15]

typedef __attribute__((ext_vector_type(8))) short short8;
typedef __attribute__((ext_vector_type(4))) float f32x4;

constexpr int T_STEPS = 48;
constexpr int F_DIM   = 16;
constexpr int H_DIM   = 32;
constexpr int ROW_SH  = 40;                    // shorts per h-row (80 B, 16B-aligned)
constexpr int H_BYTES = 16 * ROW_SH * 2;       // 1280 B
constexpr int O_FLOATS = 16 * T_STEPS;         // 768 floats = 3072 B
constexpr int WAVE_BYTES = H_BYTES + O_FLOATS * 4;

union S8 { short8 s; unsigned u[4]; };

__device__ __forceinline__ unsigned pk_bf16(float hi, float lo) {
    // (bf16(hi)<<16)|bf16(lo), round-half-up
    return __builtin_amdgcn_perm(__float_as_uint(hi) + 0x8000u,
                                 __float_as_uint(lo) + 0x8000u, 0x07060302u);
}
__device__ __forceinline__ short bf16s(float x) {
    return (short)((__float_as_uint(x) + 0x8000u) >> 16);
}
__device__ __forceinline__ float fsig(float x) {
    return __builtin_amdgcn_rcpf(1.0f + __expf(-x));
}
__device__ __forceinline__ float ftanh(float x) {
    return 1.0f - 2.0f * __builtin_amdgcn_rcpf(__expf(2.0f * x) + 1.0f);
}
#define MFMA(a, b, c) __builtin_amdgcn_mfma_f32_16x16x32_bf16(a, b, c, 0, 0, 0)
#define SWZ16(v) __int_as_float(__builtin_amdgcn_ds_swizzle(__float_as_int(v), 0x401F))

__global__ __launch_bounds__(256, 2)
void gru_mfma4(const float* __restrict__ feat,     // [B,T,F]
               const float* __restrict__ init_in,  // [B,1]
               const float* __restrict__ init_h,   // [B,H]
               const float* __restrict__ Wk,       // [17,96]
               const float* __restrict__ Rk,       // [32,96]
               const float* __restrict__ bx,       // [96]
               const float* __restrict__ bh,       // [96]
               const float* __restrict__ dw,       // [32]
               const float* __restrict__ db,       // [1]
               float* __restrict__ out)            // [B,T]
{
    __shared__ __align__(16) char lds[4 * WAVE_BYTES];
    const int lane = threadIdx.x & 63;
    const int wave = threadIdx.x >> 6;
    const int ln   = lane & 15;
    const int quad = lane >> 4;
    const int b0   = (blockIdx.x * 4 + wave) * 16;

    char*  my   = lds + wave * WAVE_BYTES;
    short* hsh  = (short*)my;
    float* obuf = (float*)(my + H_BYTES);
    unsigned* hw = (unsigned*)(hsh + ln * ROW_SH + quad * 4);   // packed h writes
    const short8* hr = (const short8*)(hsh + ln * ROW_SH + quad * 8);
    const int bpa = (lane ^ 32) << 2;                           // bpermute addr (xor32)

    // ---- weight fragments (identical staging to round 3; used as A now) ----
    S8 Wf[6], Rf[6];
#pragma unroll
    for (int tn = 0; tn < 6; ++tn) {
#pragma unroll
        for (int j = 0; j < 8; ++j) {
            const int k = quad * 8 + j;
            const int n = tn * 16 + ln;
            const float wv = (k < 16) ? Wk[(size_t)(k + 1) * 96 + n] : 0.0f;
            Wf[tn].s[j] = bf16s(wv);
            Rf[tn].s[j] = bf16s(Rk[(size_t)k * 96 + n]);
        }
    }

    // ---- per-lane gate-column constants: c = tn*16 + quad*4 + i ----
    float bz8[8], br8[8], bxh8[8], bhh8[8], wz8[8], wr8[8], wh8[8], dw8[8];
#pragma unroll
    for (int tn = 0; tn < 2; ++tn)
#pragma unroll
        for (int i = 0; i < 4; ++i) {
            const int c = tn * 16 + quad * 4 + i;
            const int idx = tn * 4 + i;
            bz8[idx]  = bx[c] + bh[c];
            br8[idx]  = bx[32 + c] + bh[32 + c];
            bxh8[idx] = bx[64 + c];
            bhh8[idx] = bh[64 + c];
            wz8[idx]  = Wk[c];          // kernel row 0 = prev_out weights
            wr8[idx]  = Wk[32 + c];
            wh8[idx]  = Wk[64 + c];
            dw8[idx]  = dw[c];
        }
    const float dbs = db[0];

    // ---- initial state (lane's batch row = ln) ----
    float hc[8];
#pragma unroll
    for (int tn = 0; tn < 2; ++tn)
#pragma unroll
        for (int i = 0; i < 4; ++i)
            hc[tn * 4 + i] = init_h[(size_t)(b0 + ln) * H_DIM + tn * 16 + quad * 4 + i];
    S8 hB;
    {
        const float* hp = init_h + (size_t)(b0 + ln) * H_DIM + quad * 8;
        const f32x4 a = *(const f32x4*)hp;
        const f32x4 b = *(const f32x4*)(hp + 4);
        hB.u[0] = pk_bf16(a[1], a[0]); hB.u[1] = pk_bf16(a[3], a[2]);
        hB.u[2] = pk_bf16(b[1], b[0]); hB.u[3] = pk_bf16(b[3], b[2]);
    }
    float po = init_in[b0 + ln];        // replicated across quads

    // ---- feat prefetch for t=0 ----
    const float* fqb = feat + (size_t)(b0 + ln) * (T_STEPS * F_DIM) + (quad & 1) * 8;
    f32x4 pa = *(const f32x4*)(fqb);
    f32x4 pb = *(const f32x4*)(fqb + 4);

    for (int t = 0; t < T_STEPS; ++t) {
        // x B-frag from prefetched regs; zero quads 2,3 (K upper half)
        S8 xa;
        xa.u[0] = pk_bf16(pa[1], pa[0]); xa.u[1] = pk_bf16(pa[3], pa[2]);
        xa.u[2] = pk_bf16(pb[1], pb[0]); xa.u[3] = pk_bf16(pb[3], pb[2]);
        const unsigned zm = (quad < 2) ? 0xFFFFFFFFu : 0u;
        xa.u[0] &= zm; xa.u[1] &= zm; xa.u[2] &= zm; xa.u[3] &= zm;

        // prefetch feat(t+1) immediately (only VMEM in the loop)
        const int t1 = (t < T_STEPS - 1) ? t + 1 : T_STEPS - 1;
        pa = *(const f32x4*)(fqb + t1 * F_DIM);
        pb = *(const f32x4*)(fqb + t1 * F_DIM + 4);

        // C-inits: bias + prev_out rank-1 term (po replicated per ln)
        f32x4 aZ[2], aR[2], aXH[2], aHH[2];
#pragma unroll
        for (int tn = 0; tn < 2; ++tn)
#pragma unroll
            for (int i = 0; i < 4; ++i) {
                const int idx = tn * 4 + i;
                aZ[tn][i]  = fmaf(po, wz8[idx], bz8[idx]);
                aR[tn][i]  = fmaf(po, wr8[idx], br8[idx]);
                aXH[tn][i] = fmaf(po, wh8[idx], bxh8[idx]);
                aHH[tn][i] = bhh8[idx];
            }
#pragma unroll
        for (int tn = 0; tn < 2; ++tn) {
            aZ[tn]  = MFMA(Wf[tn].s,     xa.s, aZ[tn]);
            aZ[tn]  = MFMA(Rf[tn].s,     hB.s, aZ[tn]);
            aR[tn]  = MFMA(Wf[2 + tn].s, xa.s, aR[tn]);
            aR[tn]  = MFMA(Rf[2 + tn].s, hB.s, aR[tn]);
            aXH[tn] = MFMA(Wf[4 + tn].s, xa.s, aXH[tn]);
            aHH[tn] = MFMA(Rf[4 + tn].s, hB.s, aHH[tn]);
        }

        // gates + h_new + dense partial (lane's batch = ln)
        float hn[8];
        float partial = 0.0f;
#pragma unroll
        for (int tn = 0; tn < 2; ++tn)
#pragma unroll
            for (int i = 0; i < 4; ++i) {
                const int idx = tn * 4 + i;
                const float zz = fsig(aZ[tn][i]);
                const float rr = fsig(aR[tn][i]);
                const float cc = ftanh(aXH[tn][i] + rr * aHH[tn][i]);
                const float h2 = cc + zz * (hc[idx] - cc);
                hc[idx] = h2;
                hn[idx] = h2;
                partial = fmaf(h2, dw8[idx], partial);
            }

        // Dense(32->1): reduce across quads (xor16 swizzle + xor32 bpermute)
        float s1 = partial + SWZ16(partial);
        s1 += __int_as_float(__builtin_amdgcn_ds_bpermute(bpa, __float_as_int(s1)));
        const float o = s1 + dbs;
        if (quad == 0) obuf[t * 16 + ln] = o;   // bank-clean: 16 consecutive banks
        po = o;

        // h C^T-layout -> B-frag via wave-private LDS (in-order DS pipe)
        hw[0] = pk_bf16(hn[1], hn[0]);
        hw[1] = pk_bf16(hn[3], hn[2]);
        hw[8] = pk_bf16(hn[5], hn[4]);          // tile 1: short-offset 16 = uint-offset 8
        hw[9] = pk_bf16(hn[7], hn[6]);
        hB.s = *hr;
    }

    // ---- flush outputs: coalesced dwordx4 ----
    const int row = lane >> 2;                  // 0..15
    const int tb  = (lane & 3) * 12;            // 0,12,24,36
    float* orow = out + (size_t)(b0 + row) * T_STEPS + tb;
#pragma unroll
    for (int k = 0; k < 3; ++k) {
        f32x4 v;
#pragma unroll
        for (int e = 0; e < 4; ++e) v[e] = obuf[(tb + k * 4 + e) * 16 + row];
        *(f32x4*)(orow + k * 4) = v;
    }
}

extern "C" void kernel_launch(void* const* d_in, const int* in_sizes, int n_in,
                              void* d_out, int out_size, void* d_ws, size_t ws_size,
                              hipStream_t stream) {
    const float* feat    = (const float*)d_in[0];
    const float* init_in = (const float*)d_in[1];
    const float* init_h  = (const float*)d_in[2];
    const float* Wk      = (const float*)d_in[3];
    const float* Rk      = (const float*)d_in[4];
    const float* bx      = (const float*)d_in[5];
    const float* bh      = (const float*)d_in[6];
    const float* dw      = (const float*)d_in[7];
    const float* db      = (const float*)d_in[8];
    float* out           = (float*)d_out;

    const int B = in_sizes[2] / H_DIM;      // 32768
    dim3 grid((unsigned)(B / 64));          // 16 rows/wave * 4 waves/block
    dim3 block(256);
    hipLaunchKernelGGL(gru_mfma4, grid, block, 0, stream,
                       feat, init_in, init_h, Wk, Rk, bx, bh, dw, db, out);
}

// Round 5
// 196.526 us; speedup vs baseline: 2.8178x; 1.0104x over previous
//
#include <hip/hip_runtime.h>

// GRU decoder via MFMA, round 5: B=32768, T=48, F=16, H=32.
// Wave owns 16 batch rows for all 48 steps (2048 waves = 2/SIMD).
// Transposed formulation: D = MFMA(A=weights, B=data), D[m=gatecol][n=batch].
// Changes vs round 4 (which stalled ~54% on two concatenated serial chains):
//  - h C->B transform: LDS write->read round trip REPLACED by 4 independent
//    ds_bpermute ops on packed bf16 pairs + 4 cndmask selects (mapping
//    verified lane-by-lane against the known-good LDS version, all 4 quads).
//    Also removes the 1.32M LDS bank conflicts of the strided h-tile.
//  - po (prev dense output) moved OFF the MFMA path: MFMAs take C = bias
//    only (x-side first -- operands ready at step start -- h-side second);
//    po enters as one fma per gate element at gate time. Dense-reduce chain
//    now runs in PARALLEL with the h-transform+MFMA chain.
//  - dense partial as a 3-deep tree (was 8-deep fma chain).
//  - obuf leading stride 17 floats -> conflict-free final flush.
// Layouts (verified m89/m91/m120):
//   C/D: col=lane&15=batch, row=(lane>>4)*4+reg=gatecol
//   A[m=lane&15][k=(lane>>4)*8+j] ; B[k=(lane>>4)*8+j][n=lane&15]

typedef __attribute__((ext_vector_type(8))) short short8;
typedef __attribute__((ext_vector_type(4))) float f32x4;

constexpr int T_STEPS = 48;
constexpr int F_DIM   = 16;
constexpr int H_DIM   = 32;
constexpr int O_STRIDE = 17;                       // floats; conflict-free flush
constexpr int WAVE_FLOATS = T_STEPS * O_STRIDE;    // 816 floats = 3264 B / wave

union S8 { short8 s; unsigned u[4]; };

__device__ __forceinline__ unsigned pk_bf16(float hi, float lo) {
    // (bf16(hi)<<16)|bf16(lo), round-half-up
    return __builtin_amdgcn_perm(__float_as_uint(hi) + 0x8000u,
                                 __float_as_uint(lo) + 0x8000u, 0x07060302u);
}
__device__ __forceinline__ short bf16s(float x) {
    return (short)((__float_as_uint(x) + 0x8000u) >> 16);
}
__device__ __forceinline__ float fsig(float x) {
    return __builtin_amdgcn_rcpf(1.0f + __expf(-x));
}
__device__ __forceinline__ float ftanh(float x) {
    return 1.0f - 2.0f * __builtin_amdgcn_rcpf(__expf(2.0f * x) + 1.0f);
}
#define MFMA(a, b, c) __builtin_amdgcn_mfma_f32_16x16x32_bf16(a, b, c, 0, 0, 0)
#define SWZ16(v) __int_as_float(__builtin_amdgcn_ds_swizzle(__float_as_int(v), 0x401F))
#define BPERM(a, v) __builtin_amdgcn_ds_bpermute((a), (v))

__global__ __launch_bounds__(256, 2)
void gru_mfma5(const float* __restrict__ feat,     // [B,T,F]
               const float* __restrict__ init_in,  // [B,1]
               const float* __restrict__ init_h,   // [B,H]
               const float* __restrict__ Wk,       // [17,96]
               const float* __restrict__ Rk,       // [32,96]
               const float* __restrict__ bx,       // [96]
               const float* __restrict__ bh,       // [96]
               const float* __restrict__ dw,       // [32]
               const float* __restrict__ db,       // [1]
               float* __restrict__ out)            // [B,T]
{
    __shared__ __align__(16) float obufA[4 * WAVE_FLOATS];
    const int lane = threadIdx.x & 63;
    const int wave = threadIdx.x >> 6;
    const int ln   = lane & 15;
    const int quad = lane >> 4;
    const int b0   = (blockIdx.x * 4 + wave) * 16;
    float* obuf = obufA + wave * WAVE_FLOATS;

    // bpermute lane schedule for the h C->B redistribution:
    //   bp1/bp2 pull from lane (ln, s1), bp3/bp4 from (ln, s1^1),
    //   s1 = bit-swapped quad.  Sources chosen by (quad&1) parity.
    const int s1  = ((quad & 1) << 1) | (quad >> 1);
    const int aA  = (ln + 16 * s1) << 2;
    const int aB  = aA ^ 64;
    const int bpa = (lane ^ 32) << 2;              // dense reduce xor32
    const bool eodd = (quad & 1) != 0;
    const bool lo2  = quad < 2;

    // ---- weight fragments (A-operand) ----
    S8 Wf[6], Rf[6];
#pragma unroll
    for (int tn = 0; tn < 6; ++tn) {
#pragma unroll
        for (int j = 0; j < 8; ++j) {
            const int k = quad * 8 + j;
            const int n = tn * 16 + ln;
            const float wv = (k < 16) ? Wk[(size_t)(k + 1) * 96 + n] : 0.0f;
            Wf[tn].s[j] = bf16s(wv);
            Rf[tn].s[j] = bf16s(Rk[(size_t)k * 96 + n]);
        }
    }

    // ---- per-lane gate-column constants: c = tn*16 + quad*4 + i ----
    float bz8[8], br8[8], bxh8[8], bhh8[8], wz8[8], wr8[8], wh8[8], dw8[8];
#pragma unroll
    for (int tn = 0; tn < 2; ++tn)
#pragma unroll
        for (int i = 0; i < 4; ++i) {
            const int c = tn * 16 + quad * 4 + i;
            const int idx = tn * 4 + i;
            bz8[idx]  = bx[c] + bh[c];
            br8[idx]  = bx[32 + c] + bh[32 + c];
            bxh8[idx] = bx[64 + c];
            bhh8[idx] = bh[64 + c];
            wz8[idx]  = Wk[c];          // kernel row 0 = prev_out weights
            wr8[idx]  = Wk[32 + c];
            wh8[idx]  = Wk[64 + c];
            dw8[idx]  = dw[c];
        }
    const float dbs = db[0];

    // ---- initial state (lane's batch row = ln) ----
    float hc[8];
#pragma unroll
    for (int tn = 0; tn < 2; ++tn)
#pragma unroll
        for (int i = 0; i < 4; ++i)
            hc[tn * 4 + i] = init_h[(size_t)(b0 + ln) * H_DIM + tn * 16 + quad * 4 + i];
    S8 hB;
    {
        const float* hp = init_h + (size_t)(b0 + ln) * H_DIM + quad * 8;
        const f32x4 a = *(const f32x4*)hp;
        const f32x4 b = *(const f32x4*)(hp + 4);
        hB.u[0] = pk_bf16(a[1], a[0]); hB.u[1] = pk_bf16(a[3], a[2]);
        hB.u[2] = pk_bf16(b[1], b[0]); hB.u[3] = pk_bf16(b[3], b[2]);
    }
    float po = init_in[b0 + ln];        // replicated across quads

    // ---- feat prefetch for t=0 ----
    const float* fqb = feat + (size_t)(b0 + ln) * (T_STEPS * F_DIM) + (quad & 1) * 8;
    f32x4 pa = *(const f32x4*)(fqb);
    f32x4 pb = *(const f32x4*)(fqb + 4);

    for (int t = 0; t < T_STEPS; ++t) {
        // x B-frag from prefetched regs; zero quads 2,3 (K upper half)
        S8 xa;
        xa.u[0] = pk_bf16(pa[1], pa[0]); xa.u[1] = pk_bf16(pa[3], pa[2]);
        xa.u[2] = pk_bf16(pb[1], pb[0]); xa.u[3] = pk_bf16(pb[3], pb[2]);
        const unsigned zm = lo2 ? 0xFFFFFFFFu : 0u;
        xa.u[0] &= zm; xa.u[1] &= zm; xa.u[2] &= zm; xa.u[3] &= zm;

        // prefetch feat(t+1) (only VMEM in the loop)
        const int t1 = (t < T_STEPS - 1) ? t + 1 : T_STEPS - 1;
        pa = *(const f32x4*)(fqb + t1 * F_DIM);
        pb = *(const f32x4*)(fqb + t1 * F_DIM + 4);

        // MFMAs, C = bias only; x-side first (ready), h-side second
        f32x4 aZ[2], aR[2], aXH[2], aHH[2];
#pragma unroll
        for (int tn = 0; tn < 2; ++tn)
#pragma unroll
            for (int i = 0; i < 4; ++i) {
                aZ[tn][i]  = bz8[tn * 4 + i];
                aR[tn][i]  = br8[tn * 4 + i];
                aXH[tn][i] = bxh8[tn * 4 + i];
                aHH[tn][i] = bhh8[tn * 4 + i];
            }
#pragma unroll
        for (int tn = 0; tn < 2; ++tn) {
            aZ[tn]  = MFMA(Wf[tn].s,     xa.s, aZ[tn]);
            aR[tn]  = MFMA(Wf[2 + tn].s, xa.s, aR[tn]);
            aXH[tn] = MFMA(Wf[4 + tn].s, xa.s, aXH[tn]);
            aZ[tn]  = MFMA(Rf[tn].s,     hB.s, aZ[tn]);
            aR[tn]  = MFMA(Rf[2 + tn].s, hB.s, aR[tn]);
            aHH[tn] = MFMA(Rf[4 + tn].s, hB.s, aHH[tn]);
        }

        // gates + h_new (po enters here, off the MFMA path)
        float hn[8];
#pragma unroll
        for (int tn = 0; tn < 2; ++tn)
#pragma unroll
            for (int i = 0; i < 4; ++i) {
                const int idx = tn * 4 + i;
                const float zz = fsig(fmaf(po, wz8[idx], aZ[tn][i]));
                const float rr = fsig(fmaf(po, wr8[idx], aR[tn][i]));
                const float cc = ftanh(fmaf(po, wh8[idx], aXH[tn][i]) + rr * aHH[tn][i]);
                const float h2 = cc + zz * (hc[idx] - cc);
                hc[idx] = h2;
                hn[idx] = h2;
            }

        // dense partial: 3-deep tree over this lane's 8 h-elements
        const float d01 = fmaf(hn[0], dw8[0], hn[1] * dw8[1]);
        const float d23 = fmaf(hn[2], dw8[2], hn[3] * dw8[3]);
        const float d45 = fmaf(hn[4], dw8[4], hn[5] * dw8[5]);
        const float d67 = fmaf(hn[6], dw8[6], hn[7] * dw8[7]);
        float partial = (d01 + d23) + (d45 + d67);

        // h C->B: 4 packed bpermutes + selects (runs parallel to reduce)
        const unsigned p01 = pk_bf16(hn[1], hn[0]);
        const unsigned p23 = pk_bf16(hn[3], hn[2]);
        const unsigned p45 = pk_bf16(hn[5], hn[4]);
        const unsigned p67 = pk_bf16(hn[7], hn[6]);
        const unsigned b1 = (unsigned)BPERM(aA, (int)(eodd ? p45 : p01));
        const unsigned b2 = (unsigned)BPERM(aA, (int)(eodd ? p67 : p23));
        const unsigned b3 = (unsigned)BPERM(aB, (int)(eodd ? p01 : p45));
        const unsigned b4 = (unsigned)BPERM(aB, (int)(eodd ? p23 : p67));
        hB.u[0] = lo2 ? b1 : b3;
        hB.u[1] = lo2 ? b2 : b4;
        hB.u[2] = lo2 ? b3 : b1;
        hB.u[3] = lo2 ? b4 : b2;

        // Dense(32->1): xor16 swizzle + xor32 bpermute
        float s = partial + SWZ16(partial);
        s += __int_as_float(BPERM(bpa, __float_as_int(s)));
        const float o = s + dbs;
        if (quad == 0) obuf[t * O_STRIDE + ln] = o;
        po = o;
    }

    // ---- flush outputs: coalesced dwordx4 ----
    const int row = lane >> 2;                  // 0..15
    const int tb  = (lane & 3) * 12;            // 0,12,24,36
    float* orow = out + (size_t)(b0 + row) * T_STEPS + tb;
#pragma unroll
    for (int k = 0; k < 3; ++k) {
        f32x4 v;
#pragma unroll
        for (int e2 = 0; e2 < 4; ++e2) v[e2] = obuf[(tb + k * 4 + e2) * O_STRIDE + row];
        *(f32x4*)(orow + k * 4) = v;
    }
}

extern "C" void kernel_launch(void* const* d_in, const int* in_sizes, int n_in,
                              void* d_out, int out_size, void* d_ws, size_t ws_size,
                              hipStream_t stream) {
    const float* feat    = (const float*)d_in[0];
    const float* init_in = (const float*)d_in[1];
    const float* init_h  = (const float*)d_in[2];
    const float* Wk      = (const float*)d_in[3];
    const float* Rk      = (const float*)d_in[4];
    const float* bx      = (const float*)d_in[5];
    const float* bh      = (const float*)d_in[6];
    const float* dw      = (const float*)d_in[7];
    const float* db      = (const float*)d_in[8];
    float* out           = (float*)d_out;

    const int B = in_sizes[2] / H_DIM;      // 32768
    dim3 grid((unsigned)(B / 64));          // 16 rows/wave * 4 waves/block
    dim3 block(256);
    hipLaunchKernelGGL(gru_mfma5, grid, block, 0, stream,
                       feat, init_in, init_h, Wk, Rk, bx, bh, dw, db, out);
}

// Round 7
// 193.259 us; speedup vs baseline: 2.8654x; 1.0169x over previous
//
#include <hip/hip_runtime.h>

// GRU decoder via MFMA, round 7 (= round 6 + compile fix): B=32768, T=48, F=16, H=32.
// PAIR-SPLIT: block = 128 thr = 2 waves co-owning 16 batch rows; wave w
// computes only gate/hidden columns [16w,16w+16): 6 MFMAs + 4 activation
// elements per lane per step (half of round 5). Machine-wide work constant,
// wave count doubles to 4096 = 4/SIMD -> latency hiding.
// Exchange of h_new (bf16, B-frag tile) + dense half-sums through
// double-buffered LDS with ONE raw s_barrier per step, preceded by
// s_waitcnt lgkmcnt(0) ONLY (imm 0xC07F) -- NOT __syncthreads(), whose
// vmcnt(0) would drain the feat prefetch every step (m97 barrier lesson).
// log2e folded into weights: sigmoid args pre-scaled by -log2(e), tanh arg
// by 2log2(e) -> every activation is rcp(1+exp2(x)) via v_exp_f32
// (__builtin_amdgcn_exp2f -- NOT __exp2f, which is not a HIP device fn).
// Layouts (verified m89/m91/m120):
//   D[m=gatecol][n=batchcol]: col=lane&15=batch, row=(lane>>4)*4+reg=gatecol
//   A[m=lane&15][k=(lane>>4)*8+j] ; B[k=(lane>>4)*8+j][n=lane&15]

typedef __attribute__((ext_vector_type(8))) short short8;
typedef __attribute__((ext_vector_type(4))) float f32x4;

constexpr int T_STEPS  = 48;
constexpr int F_DIM    = 16;
constexpr int H_DIM    = 32;
constexpr int ROW_SH   = 40;              // shorts per h-row (80 B, 16B-aligned)
constexpr int HX_SH    = 16 * ROW_SH;     // one h buffer: 640 shorts
constexpr int O_STRIDE = 17;              // obuf leading stride (floats)

union S8 { short8 s; unsigned u[4]; };

__device__ __forceinline__ unsigned pk_bf16(float hi, float lo) {
    // (bf16(hi)<<16)|bf16(lo), round-half-up
    return __builtin_amdgcn_perm(__float_as_uint(hi) + 0x8000u,
                                 __float_as_uint(lo) + 0x8000u, 0x07060302u);
}
__device__ __forceinline__ short bf16s(float x) {
    return (short)((__float_as_uint(x) + 0x8000u) >> 16);
}
__device__ __forceinline__ float rcpf(float x) { return __builtin_amdgcn_rcpf(x); }
__device__ __forceinline__ float ex2(float x)  { return __builtin_amdgcn_exp2f(x); }
#define MFMA(a, b, c) __builtin_amdgcn_mfma_f32_16x16x32_bf16(a, b, c, 0, 0, 0)
#define SWZ16(v) __int_as_float(__builtin_amdgcn_ds_swizzle(__float_as_int(v), 0x401F))
#define BPERM(a, v) __builtin_amdgcn_ds_bpermute((a), (v))

__global__ __launch_bounds__(128, 4)
void gru_mfma7(const float* __restrict__ feat,     // [B,T,F]
               const float* __restrict__ init_in,  // [B,1]
               const float* __restrict__ init_h,   // [B,H]
               const float* __restrict__ Wk,       // [17,96]
               const float* __restrict__ Rk,       // [32,96]
               const float* __restrict__ bx,       // [96]
               const float* __restrict__ bh,       // [96]
               const float* __restrict__ dw,       // [32]
               const float* __restrict__ db,       // [1]
               float* __restrict__ out)            // [B,T]
{
    __shared__ __align__(16) short hx[2 * HX_SH];          // double-buffered h tile
    __shared__ float posum[2][2][16];                      // [parity][wave][col]
    __shared__ __align__(16) float obuf[T_STEPS * O_STRIDE];

    const int lane = threadIdx.x & 63;
    const int w    = threadIdx.x >> 6;        // 0/1: hidden half owned
    const int ln   = lane & 15;               // batch col
    const int quad = lane >> 4;
    const int b0   = blockIdx.x * 16;
    const int bpa  = (lane ^ 32) << 2;        // xor32 bpermute addr

    const float SZ = -1.44269504088896340736f;   // -log2(e)  (sigmoid args)
    const float SC =  2.88539008177792681472f;   // 2*log2(e) (tanh arg)

    // ---- weight fragments for this wave's hidden half (A-operand) ----
    S8 Wfz, Wfr, Wfh, Rfz, Rfr, Rfh;
#pragma unroll
    for (int j = 0; j < 8; ++j) {
        const int k = quad * 8 + j;
        const int n = w * 16 + ln;
        const float wz = (k < 16) ? SZ * Wk[(size_t)(k + 1) * 96 + n]      : 0.0f;
        const float wr = (k < 16) ? SZ * Wk[(size_t)(k + 1) * 96 + 32 + n] : 0.0f;
        const float wh = (k < 16) ? SC * Wk[(size_t)(k + 1) * 96 + 64 + n] : 0.0f;
        Wfz.s[j] = bf16s(wz); Wfr.s[j] = bf16s(wr); Wfh.s[j] = bf16s(wh);
        Rfz.s[j] = bf16s(SZ * Rk[(size_t)k * 96 + n]);
        Rfr.s[j] = bf16s(SZ * Rk[(size_t)k * 96 + 32 + n]);
        Rfh.s[j] = bf16s(SC * Rk[(size_t)k * 96 + 64 + n]);
    }

    // ---- per-lane constants for this wave's 4 gate elements ----
    float bz4[4], br4[4], bxh4[4], bhh4[4], wz4[4], wr4[4], wh4[4], dw4[4];
#pragma unroll
    for (int i = 0; i < 4; ++i) {
        const int c = w * 16 + quad * 4 + i;       // hidden unit index in [0,32)
        bz4[i]  = SZ * (bx[c] + bh[c]);
        br4[i]  = SZ * (bx[32 + c] + bh[32 + c]);
        bxh4[i] = SC * bx[64 + c];
        bhh4[i] = SC * bh[64 + c];
        wz4[i]  = SZ * Wk[c];                      // kernel row 0 = prev_out
        wr4[i]  = SZ * Wk[32 + c];
        wh4[i]  = SC * Wk[64 + c];
        dw4[i]  = dw[c];
    }
    const float dbs = db[0];

    // ---- initial state ----
    float hc[4];
#pragma unroll
    for (int i = 0; i < 4; ++i)
        hc[i] = init_h[(size_t)(b0 + ln) * H_DIM + w * 16 + quad * 4 + i];
    S8 hB;                                         // full-H B-frag (both halves)
    {
        const float* hp = init_h + (size_t)(b0 + ln) * H_DIM + quad * 8;
        const f32x4 a = *(const f32x4*)hp;
        const f32x4 b = *(const f32x4*)(hp + 4);
        hB.u[0] = pk_bf16(a[1], a[0]); hB.u[1] = pk_bf16(a[3], a[2]);
        hB.u[2] = pk_bf16(b[1], b[0]); hB.u[3] = pk_bf16(b[3], b[2]);
    }
    float po = init_in[b0 + ln];

    // ---- feat prefetch (both waves load the twin rows -> L1 hits) ----
    const float* fqb = feat + (size_t)(b0 + ln) * (T_STEPS * F_DIM) + (quad & 1) * 8;
    f32x4 pa = *(const f32x4*)(fqb);
    f32x4 pb = *(const f32x4*)(fqb + 4);

    // LDS addresses for the h exchange
    unsigned* hwr = (unsigned*)(hx + ln * ROW_SH + w * 16 + quad * 4);  // write own half
    const short8* hrd = (const short8*)(hx + ln * ROW_SH + quad * 8);   // read full

    for (int t = 0; t < T_STEPS; ++t) {
        const int p = t & 1;                       // LDS buffer parity

        // x B-frag from prefetched regs; zero K upper half (quads 2,3)
        S8 xa;
        xa.u[0] = pk_bf16(pa[1], pa[0]); xa.u[1] = pk_bf16(pa[3], pa[2]);
        xa.u[2] = pk_bf16(pb[1], pb[0]); xa.u[3] = pk_bf16(pb[3], pb[2]);
        const unsigned zm = (quad < 2) ? 0xFFFFFFFFu : 0u;
        xa.u[0] &= zm; xa.u[1] &= zm; xa.u[2] &= zm; xa.u[3] &= zm;

        // prefetch feat(t+1) -- stays in flight across the raw barrier
        const int t1 = (t < T_STEPS - 1) ? t + 1 : T_STEPS - 1;
        pa = *(const f32x4*)(fqb + t1 * F_DIM);
        pb = *(const f32x4*)(fqb + t1 * F_DIM + 4);

        // 6 MFMAs for this wave's hidden half
        f32x4 aZ  = {bz4[0],  bz4[1],  bz4[2],  bz4[3]};
        f32x4 aR  = {br4[0],  br4[1],  br4[2],  br4[3]};
        f32x4 aXH = {bxh4[0], bxh4[1], bxh4[2], bxh4[3]};
        f32x4 aHH = {bhh4[0], bhh4[1], bhh4[2], bhh4[3]};
        aZ  = MFMA(Wfz.s, xa.s, aZ);
        aR  = MFMA(Wfr.s, xa.s, aR);
        aXH = MFMA(Wfh.s, xa.s, aXH);
        aZ  = MFMA(Rfz.s, hB.s, aZ);
        aR  = MFMA(Rfr.s, hB.s, aR);
        aHH = MFMA(Rfh.s, hB.s, aHH);

        // gates (pre-scaled: activation = rcp(1+exp2(x)))
        float hn[4];
#pragma unroll
        for (int i = 0; i < 4; ++i) {
            const float zz = rcpf(1.0f + ex2(fmaf(po, wz4[i], aZ[i])));
            const float rr = rcpf(1.0f + ex2(fmaf(po, wr4[i], aR[i])));
            const float vv = fmaf(rr, aHH[i], fmaf(po, wh4[i], aXH[i]));
            const float cc = fmaf(-2.0f, rcpf(1.0f + ex2(vv)), 1.0f);  // tanh
            const float h2 = cc + zz * (hc[i] - cc);
            hc[i] = h2;
            hn[i] = h2;
        }

        // dense half-sum over this wave's 16 hidden units
        const float d01 = fmaf(hn[0], dw4[0], hn[1] * dw4[1]);
        const float d23 = fmaf(hn[2], dw4[2], hn[3] * dw4[3]);
        float s = d01 + d23;
        s += SWZ16(s);
        s += __int_as_float(BPERM(bpa, __float_as_int(s)));   // sum over quads

        // publish own half: h_new (2x packed u32) + half-sum
        unsigned* hw = hwr + p * (HX_SH / 2);      // HX_SH shorts = HX_SH/2 uints
        hw[0] = pk_bf16(hn[1], hn[0]);
        hw[1] = pk_bf16(hn[3], hn[2]);
        if (lane < 16) posum[p][w][lane] = s;

        // ONE raw barrier: wait DS writes (lgkm only), NOT the vmem prefetch
        __builtin_amdgcn_s_waitcnt(0xC07F);        // lgkmcnt(0), vmcnt/exp free
        __builtin_amdgcn_s_barrier();

        // read full h B-frag + other half-sum
        hB.s = hrd[p * (HX_SH / 8)];               // short8 units: HX_SH/8 per buf
        const float os = posum[p][1 - w][ln];
        po = s + os + dbs;
        if (w == 0 && lane < 16) obuf[t * O_STRIDE + lane] = po;
    }

    // ---- flush outputs (wave 0): coalesced dwordx4 ----
    if (w == 0) {
        const int row = lane >> 2;                 // 0..15
        const int tb  = (lane & 3) * 12;           // 0,12,24,36
        float* orow = out + (size_t)(b0 + row) * T_STEPS + tb;
#pragma unroll
        for (int k = 0; k < 3; ++k) {
            f32x4 v;
#pragma unroll
            for (int e = 0; e < 4; ++e) v[e] = obuf[(tb + k * 4 + e) * O_STRIDE + row];
            *(f32x4*)(orow + k * 4) = v;
        }
    }
}

extern "C" void kernel_launch(void* const* d_in, const int* in_sizes, int n_in,
                              void* d_out, int out_size, void* d_ws, size_t ws_size,
                              hipStream_t stream) {
    const float* feat    = (const float*)d_in[0];
    const float* init_in = (const float*)d_in[1];
    const float* init_h  = (const float*)d_in[2];
    const float* Wk      = (const float*)d_in[3];
    const float* Rk      = (const float*)d_in[4];
    const float* bx      = (const float*)d_in[5];
    const float* bh      = (const float*)d_in[6];
    const float* dw      = (const float*)d_in[7];
    const float* db      = (const float*)d_in[8];
    float* out           = (float*)d_out;

    const int B = in_sizes[2] / H_DIM;      // 32768
    dim3 grid((unsigned)(B / 16));          // one 2-wave block per 16 batch rows
    dim3 block(128);
    hipLaunchKernelGGL(gru_mfma7, grid, block, 0, stream,
                       feat, init_in, init_h, Wk, Rk, bx, bh, dw, db, out);
}